// Round 2
// baseline (19302.924 us; speedup 1.0000x reference)
//
#include <hip/hip_runtime.h>
#include <hip/hip_cooperative_groups.h>

namespace cg = cooperative_groups;

#define BB  64
#define TT  256
#define INF 512
#define HH  1024
#define CC  128

typedef __attribute__((ext_vector_type(8))) short bf16x8;
typedef __attribute__((ext_vector_type(4))) float f32x4;

// LDS leading dims padded so row stride stays 16B-aligned and off power-of-2.
#define W0_LD 1544   // 1536 + 8
#define W1_LD 2056   // 2048 + 8
#define WC_LD 1032   // 1024 + 8
#define SMEM_BYTES ((16*W0_LD + 16*W1_LD + 16*WC_LD)*2 + 4*16*17*4)  // 152576 B

__device__ __forceinline__ unsigned short f2bf(float f) {
    union { float f; unsigned u; } v; v.f = f;
    unsigned r = v.u + 0x7fffu + ((v.u >> 16) & 1u);   // round-to-nearest-even
    return (unsigned short)(r >> 16);
}
__device__ __forceinline__ float sigm(float x) { return 1.f / (1.f + __expf(-x)); }

__global__ __launch_bounds__(256, 1)
void lstm_persist(const float* __restrict__ xs,
                  const float* __restrict__ Wih0, const float* __restrict__ Whh0,
                  const float* __restrict__ bih0, const float* __restrict__ bhh0,
                  const float* __restrict__ Wih1, const float* __restrict__ Whh1,
                  const float* __restrict__ bih1, const float* __restrict__ bhh1,
                  const float* __restrict__ Wcls, const float* __restrict__ bcls,
                  float* __restrict__ out,            // f32 logits [B][C][2T]
                  unsigned short* __restrict__ ws)    // h double buffers (bf16)
{
    extern __shared__ char smem[];
    unsigned short* W0s = (unsigned short*)smem;           // [16][W0_LD]  [W_hh0 | W_ih0]
    unsigned short* W1s = W0s + 16*W0_LD;                  // [16][W1_LD]  [W_ih1 | W_hh1]
    unsigned short* WCs = W1s + 16*W1_LD;                  // [16][WC_LD]  W_cls slice
    float* gsc = (float*)(smem + (16*W0_LD + 16*W1_LD + 16*WC_LD)*2); // [4][16][17]

    const int blk   = blockIdx.x;        // 0..255, owns h-cols 4*blk..4*blk+3 (both layers)
    const int tid   = threadIdx.x;
    const int wave  = tid >> 6;          // 0..3 -> batch rows 16w..16w+15
    const int lane  = tid & 63;
    const int col16 = lane & 15;
    const int kgrp  = (lane >> 4) << 3;  // 0,8,16,24

    unsigned short* h0b0 = ws;
    unsigned short* h0b1 = ws + BB*HH;
    unsigned short* h1b0 = ws + 2*BB*HH;
    unsigned short* h1b1 = ws + 3*BB*HH;

    // ---- prologue: weights -> LDS (bf16). LDS row r <-> gate row 4*blk + (r&3) + H*(r>>2)
    for (int i = tid; i < 16*1536; i += 256) {
        int r = i / 1536, k = i - r*1536;
        int gr = 4*blk + (r & 3) + HH*(r >> 2);
        float v = (k < HH) ? Whh0[gr*HH + k] : Wih0[gr*INF + (k - HH)];
        W0s[r*W0_LD + k] = f2bf(v);
    }
    for (int i = tid; i < 16*2048; i += 256) {
        int r = i >> 11, k = i & 2047;
        int gr = 4*blk + (r & 3) + HH*(r >> 2);
        float v = (k < HH) ? Wih1[gr*HH + k] : Whh1[gr*HH + (k - HH)];
        W1s[r*W1_LD + k] = f2bf(v);
    }
    if (blk < 64) {  // classifier duty blocks: cls cols 16*(blk&7)..+15
        int cb = (blk & 7) << 4;
        for (int i = tid; i < 16*1024; i += 256) {
            int r = i >> 10, k = i & 1023;
            WCs[r*WC_LD + k] = f2bf(Wcls[(cb + r)*HH + k]);
        }
    }
    const int   grl   = 4*blk + (col16 & 3) + HH*(col16 >> 2);
    const float bias0 = bih0[grl] + bhh0[grl];
    const float bias1 = bih1[grl] + bhh1[grl];
    const float biasc = (blk < 64) ? bcls[((blk & 7) << 4) + col16] : 0.f;

    for (int i = blk*256 + tid; i < 4*BB*HH; i += 256*256) ws[i] = 0;

    float c0 = 0.f, c1 = 0.f;   // cell state in registers: (row=16w+(lane>>2), col=4*blk+(lane&3))

    cg::grid_group grid = cg::this_grid();
    __syncthreads();
    grid.sync();

    for (int t = 0; t <= TT; ++t) {
        const int q = t & 1;
        const unsigned short* h0rd = q ? h0b1 : h0b0;   // h0(t-1)
        unsigned short*       h0wr = q ? h0b0 : h0b1;   // h0(t)
        const unsigned short* h1rd = q ? h1b1 : h1b0;   // h1(t-1)
        unsigned short*       h1wr = q ? h1b0 : h1b1;   // h1(t)

        if (t < TT) {
            // ---- phase 1: gates0 = [h0(t-1) | x_t] @ W0^T + b  (K = 1536)
            f32x4 accA = { bias0, bias0, bias0, bias0 };
            f32x4 accB = { 0.f, 0.f, 0.f, 0.f };
            const int arow = (wave << 4) + col16;
            const unsigned short* hrow = h0rd + arow*HH;
            const float*          xrow = xs + (arow*TT + t)*INF;
            const unsigned short* brow = W0s + col16*W0_LD + kgrp;
            for (int kc = 0; kc < 32; kc += 2) {   // h-part, 2 chains
                const bf16x8 a0 = *(const bf16x8*)(hrow + (kc << 5) + kgrp);
                const bf16x8 b0 = *(const bf16x8*)(brow + (kc << 5));
                accA = __builtin_amdgcn_mfma_f32_16x16x32_bf16(a0, b0, accA, 0, 0, 0);
                const bf16x8 a1 = *(const bf16x8*)(hrow + ((kc+1) << 5) + kgrp);
                const bf16x8 b1 = *(const bf16x8*)(brow + ((kc+1) << 5));
                accB = __builtin_amdgcn_mfma_f32_16x16x32_bf16(a1, b1, accB, 0, 0, 0);
            }
            for (int kc = 32; kc < 48; kc += 2) {  // x-part, convert f32->bf16 inline
                #pragma unroll
                for (int u = 0; u < 2; ++u) {
                    const float* xp = xrow + (((kc+u) << 5) + kgrp - HH);
                    const float4 x0 = *(const float4*)xp;
                    const float4 x1 = *(const float4*)(xp + 4);
                    bf16x8 a;
                    a[0]=(short)f2bf(x0.x); a[1]=(short)f2bf(x0.y); a[2]=(short)f2bf(x0.z); a[3]=(short)f2bf(x0.w);
                    a[4]=(short)f2bf(x1.x); a[5]=(short)f2bf(x1.y); a[6]=(short)f2bf(x1.z); a[7]=(short)f2bf(x1.w);
                    const bf16x8 b = *(const bf16x8*)(brow + ((kc+u) << 5));
                    if (u == 0) accA = __builtin_amdgcn_mfma_f32_16x16x32_bf16(a, b, accA, 0, 0, 0);
                    else        accB = __builtin_amdgcn_mfma_f32_16x16x32_bf16(a, b, accB, 0, 0, 0);
                }
            }
            #pragma unroll
            for (int qq = 0; qq < 4; ++qq)
                gsc[wave*272 + (((lane >> 4) << 2) + qq)*17 + col16] = accA[qq] + accB[qq];
        }
        __syncthreads();
        if (t < TT) {
            // elementwise LSTM cell, layer 0
            const int rloc = lane >> 2, jj = lane & 3;
            const float* g = gsc + wave*272 + rloc*17;
            const float ig = sigm(g[jj]), fg = sigm(g[4+jj]);
            const float gt = tanhf(g[8+jj]), og = sigm(g[12+jj]);
            c0 = fg*c0 + ig*gt;
            const float h = og * tanhf(c0);
            h0wr[((wave << 4) + rloc)*HH + (blk << 2) + jj] = f2bf(h);
        }
        if (blk < 32 && wave == (blk >> 3) && t >= 1) {
            // ---- l1(t-1): one 16x16 wave-tile, rows 16w.., cls cols 16*(blk&7)..
            f32x4 acc = { biasc, biasc, biasc, biasc };
            const unsigned short* hrow = h1rd + (((wave << 4) + col16))*HH;
            const unsigned short* brow = WCs + col16*WC_LD + kgrp;
            for (int kc = 0; kc < 32; ++kc) {
                const bf16x8 a = *(const bf16x8*)(hrow + (kc << 5) + kgrp);
                const bf16x8 b = *(const bf16x8*)(brow + (kc << 5));
                acc = __builtin_amdgcn_mfma_f32_16x16x32_bf16(a, b, acc, 0, 0, 0);
            }
            const int cc = ((blk & 7) << 4) + col16;
            #pragma unroll
            for (int qq = 0; qq < 4; ++qq) {
                const int br = (wave << 4) + ((lane >> 4) << 2) + qq;
                out[(br*CC + cc)*(2*TT) + (((t-1) << 1) + 1)] = acc[qq];
            }
        }
        grid.sync();   // h0(t) visible everywhere

        if (t < TT) {
            // ---- phase 2: gates1 = [h0(t) | h1(t-1)] @ W1^T + b  (K = 2048)
            f32x4 accA = { bias1, bias1, bias1, bias1 };
            f32x4 accB = { 0.f, 0.f, 0.f, 0.f };
            const int arow = (wave << 4) + col16;
            const unsigned short* h0r = h0wr + arow*HH;
            const unsigned short* h1r = h1rd + arow*HH;
            const unsigned short* brow = W1s + col16*W1_LD + kgrp;
            for (int kc = 0; kc < 32; kc += 2) {   // h0(t) part
                const bf16x8 a0 = *(const bf16x8*)(h0r + (kc << 5) + kgrp);
                const bf16x8 b0 = *(const bf16x8*)(brow + (kc << 5));
                accA = __builtin_amdgcn_mfma_f32_16x16x32_bf16(a0, b0, accA, 0, 0, 0);
                const bf16x8 a1 = *(const bf16x8*)(h0r + ((kc+1) << 5) + kgrp);
                const bf16x8 b1 = *(const bf16x8*)(brow + ((kc+1) << 5));
                accB = __builtin_amdgcn_mfma_f32_16x16x32_bf16(a1, b1, accB, 0, 0, 0);
            }
            for (int kc = 32; kc < 64; kc += 2) {  // h1(t-1) part
                const bf16x8 a0 = *(const bf16x8*)(h1r + ((kc << 5) - HH) + kgrp);
                const bf16x8 b0 = *(const bf16x8*)(brow + (kc << 5));
                accA = __builtin_amdgcn_mfma_f32_16x16x32_bf16(a0, b0, accA, 0, 0, 0);
                const bf16x8 a1 = *(const bf16x8*)(h1r + (((kc+1) << 5) - HH) + kgrp);
                const bf16x8 b1 = *(const bf16x8*)(brow + ((kc+1) << 5));
                accB = __builtin_amdgcn_mfma_f32_16x16x32_bf16(a1, b1, accB, 0, 0, 0);
            }
            #pragma unroll
            for (int qq = 0; qq < 4; ++qq)
                gsc[wave*272 + (((lane >> 4) << 2) + qq)*17 + col16] = accA[qq] + accB[qq];
            __syncthreads();
            {
                const int rloc = lane >> 2, jj = lane & 3;
                const float* g = gsc + wave*272 + rloc*17;
                const float ig = sigm(g[jj]), fg = sigm(g[4+jj]);
                const float gt = tanhf(g[8+jj]), og = sigm(g[12+jj]);
                c1 = fg*c1 + ig*gt;
                const float h = og * tanhf(c1);
                h1wr[((wave << 4) + rloc)*HH + (blk << 2) + jj] = f2bf(h);
            }
            if (blk >= 32 && blk < 64 && wave == ((blk - 32) >> 3)) {
                // ---- l0(t)
                f32x4 acc2 = { biasc, biasc, biasc, biasc };
                const unsigned short* hrow = h0wr + (((wave << 4) + col16))*HH;
                const unsigned short* brow2 = WCs + col16*WC_LD + kgrp;
                for (int kc = 0; kc < 32; ++kc) {
                    const bf16x8 a = *(const bf16x8*)(hrow + (kc << 5) + kgrp);
                    const bf16x8 b = *(const bf16x8*)(brow2 + (kc << 5));
                    acc2 = __builtin_amdgcn_mfma_f32_16x16x32_bf16(a, b, acc2, 0, 0, 0);
                }
                const int cc = ((blk & 7) << 4) + col16;
                #pragma unroll
                for (int qq = 0; qq < 4; ++qq) {
                    const int br = (wave << 4) + ((lane >> 4) << 2) + qq;
                    out[(br*CC + cc)*(2*TT) + (t << 1)] = acc2[qq];
                }
            }
            grid.sync();   // h1(t) visible everywhere
        }
    }
}

extern "C" void kernel_launch(void* const* d_in, const int* in_sizes, int n_in,
                              void* d_out, int out_size, void* d_ws, size_t ws_size,
                              hipStream_t stream) {
    const float* xs   = (const float*)d_in[0];
    const float* Wih0 = (const float*)d_in[1];
    const float* Whh0 = (const float*)d_in[2];
    const float* bih0 = (const float*)d_in[3];
    const float* bhh0 = (const float*)d_in[4];
    const float* Wih1 = (const float*)d_in[5];
    const float* Whh1 = (const float*)d_in[6];
    const float* bih1 = (const float*)d_in[7];
    const float* bhh1 = (const float*)d_in[8];
    const float* Wcls = (const float*)d_in[9];
    const float* bcls = (const float*)d_in[10];
    float* out = (float*)d_out;                     // f32 output (reference dtype)
    unsigned short* wsp = (unsigned short*)d_ws;    // needs 512 KB

    (void)hipFuncSetAttribute((const void*)lstm_persist,
                              hipFuncAttributeMaxDynamicSharedMemorySize, SMEM_BYTES);

    void* args[] = { (void*)&xs, (void*)&Wih0, (void*)&Whh0, (void*)&bih0, (void*)&bhh0,
                     (void*)&Wih1, (void*)&Whh1, (void*)&bih1, (void*)&bhh1,
                     (void*)&Wcls, (void*)&bcls, (void*)&out, (void*)&wsp };
    (void)hipLaunchCooperativeKernel((const void*)lstm_persist, dim3(256), dim3(256),
                                     args, SMEM_BYTES, stream);
}

// Round 3
// 7220.301 us; speedup vs baseline: 2.6734x; 2.6734x over previous
//
#include <hip/hip_runtime.h>

#define BB  64
#define TT  256
#define INF 512
#define HH  1024
#define CC  128

typedef __attribute__((ext_vector_type(8))) short bf16x8;
typedef __attribute__((ext_vector_type(4))) float f32x4;
typedef unsigned long long ull_t;
typedef unsigned short u16;

#define W0_LD 1544   // 1536+8 : row stride 3088B = 772 dw == 4 mod 32 banks (2-way, free)
#define W1_LD 2056   // 2048+8 : 4112B = 1028 dw == 4 mod 32
#define WC_LD 1032   // 1024+8 : 2064B =  516 dw == 4 mod 32
#define GSC_OFF (16*W0_LD + 16*W1_LD + 16*WC_LD)           // ushort units = 74112
#define SMEM_BYTES (GSC_OFF*2 + 2*(4*16*17)*4)             // 148224 + 8704 = 156928 B

#define WS_HBYTES (4*BB*HH*2)        // 524288 B : h0[2], h1[2] bf16 double buffers
#define WS_BARWORDS 1536             // barrier region (u32)
#define WS_ZERO_BYTES (WS_HBYTES + WS_BARWORDS*4)

__device__ __forceinline__ u16 f2bf(float f) {
    union { float f; unsigned u; } v; v.f = f;
    unsigned r = v.u + 0x7fffu + ((v.u >> 16) & 1u);   // RNE
    return (u16)(r >> 16);
}
__device__ __forceinline__ float sigm(float x) { return 1.f / (1.f + __expf(-x)); }

#define MFMA(a,b,c) __builtin_amdgcn_mfma_f32_16x16x32_bf16((a),(b),(c),0,0,0)

__global__ __launch_bounds__(256, 1)
void lstm_persist(const float* __restrict__ xs,
                  const float* __restrict__ Wih0, const float* __restrict__ Whh0,
                  const float* __restrict__ bih0, const float* __restrict__ bhh0,
                  const float* __restrict__ Wih1, const float* __restrict__ Whh1,
                  const float* __restrict__ bih1, const float* __restrict__ bhh1,
                  const float* __restrict__ Wcls, const float* __restrict__ bcls,
                  float* __restrict__ out,          // f32 [B][C][2T], nt-stored
                  u16* __restrict__ hws,            // h double buffers (bf16)
                  unsigned* __restrict__ bar)       // barrier counters (zeroed by memset)
{
    extern __shared__ char smem[];
    u16* W0s = (u16*)smem;              // [16][W0_LD]  [W_hh0 | W_ih0]
    u16* W1s = W0s + 16*W0_LD;          // [16][W1_LD]  [W_ih1 | W_hh1]
    u16* WCs = W1s + 16*W1_LD;          // [16][WC_LD]  W_cls slice (blocks 0..63)
    float* gsc0 = (float*)(smem + GSC_OFF*2);       // [4][16][17]
    float* gsc1 = gsc0 + 4*16*17;                   // [4][16][17]

    const int blk   = blockIdx.x;       // 0..255, owns h-cols 4*blk..4*blk+3 (both layers)
    const int tid   = threadIdx.x;
    const int wave  = tid >> 6;         // batch rows 16w..16w+15
    const int lane  = tid & 63;
    const int col16 = lane & 15;
    const int kgrp  = (lane >> 4) << 3; // 0,8,16,24

    u16* h0buf[2] = { hws,             hws + BB*HH };
    u16* h1buf[2] = { hws + 2*BB*HH,   hws + 3*BB*HH };

    // ---- prologue: weights -> LDS (bf16)
    for (int i = tid; i < 16*1536; i += 256) {
        int r = i / 1536, k = i - r*1536;
        int gr = 4*blk + (r & 3) + HH*(r >> 2);
        float v = (k < HH) ? Whh0[gr*HH + k] : Wih0[gr*INF + (k - HH)];
        W0s[r*W0_LD + k] = f2bf(v);
    }
    for (int i = tid; i < 16*2048; i += 256) {
        int r = i >> 11, k = i & 2047;
        int gr = 4*blk + (r & 3) + HH*(r >> 2);
        float v = (k < HH) ? Wih1[gr*HH + k] : Whh1[gr*HH + (k - HH)];
        W1s[r*W1_LD + k] = f2bf(v);
    }
    if (blk < 64) {
        int cb = (blk & 7) << 4;
        for (int i = tid; i < 16*1024; i += 256) {
            int r = i >> 10, k = i & 1023;
            WCs[r*WC_LD + k] = f2bf(Wcls[(cb + r)*HH + k]);
        }
    }
    const int   grl   = 4*blk + (col16 & 3) + HH*(col16 >> 2);
    const float bias0 = bih0[grl] + bhh0[grl];
    const float bias1 = bih1[grl] + bhh1[grl];
    const float biasc = (blk < 64) ? bcls[((blk & 7) << 4) + col16] : 0.f;

    float c0 = 0.f, c1 = 0.f;
    __syncthreads();

    const int  arow = (wave << 4) + col16;
    const u16* w0p  = W0s + col16*W0_LD + kgrp;
    const u16* w1p  = W1s + col16*W1_LD + kgrp;
    const u16* wcp  = WCs + col16*WC_LD + kgrp;

    for (int t = 0; t <= TT; ++t) {
        const u16* h0rd = h0buf[(t + 1) & 1];   // h0(t-1)
        u16*       h0wr = h0buf[t & 1];         // h0(t)
        const u16* h1rd = h1buf[t & 1];         // h1(t-2)
        u16*       h1wr = h1buf[(t + 1) & 1];   // h1(t-1)

        f32x4 g0A = { bias0, bias0, bias0, bias0 }, g0B = { 0.f, 0.f, 0.f, 0.f };
        f32x4 g1A = { bias1, bias1, bias1, bias1 }, g1B = { 0.f, 0.f, 0.f, 0.f };

        const u16* h0p = h0rd + arow*HH + kgrp;
        const u16* h1p = h1rd + arow*HH + kgrp;

        if (t < TT) {
            // gates0(t) h-part fused with gates1(t-1) h0-part: shared A fragments
            #pragma unroll 4
            for (int kc = 0; kc < 32; ++kc) {
                const bf16x8 a  = *(const bf16x8*)(h0p + (kc << 5));
                const bf16x8 b0 = *(const bf16x8*)(w0p + (kc << 5));
                const bf16x8 b1 = *(const bf16x8*)(w1p + (kc << 5));
                if (kc & 1) { g0B = MFMA(a, b0, g0B); g1B = MFMA(a, b1, g1B); }
                else        { g0A = MFMA(a, b0, g0A); g1A = MFMA(a, b1, g1A); }
            }
            // gates0 x-part (f32 -> bf16 inline)
            const float* xp = xs + (arow*TT + t)*INF + kgrp;
            #pragma unroll 4
            for (int kc = 0; kc < 16; ++kc) {
                const float4 x0 = *(const float4*)(xp + (kc << 5));
                const float4 x1 = *(const float4*)(xp + (kc << 5) + 4);
                bf16x8 a;
                a[0]=(short)f2bf(x0.x); a[1]=(short)f2bf(x0.y); a[2]=(short)f2bf(x0.z); a[3]=(short)f2bf(x0.w);
                a[4]=(short)f2bf(x1.x); a[5]=(short)f2bf(x1.y); a[6]=(short)f2bf(x1.z); a[7]=(short)f2bf(x1.w);
                const bf16x8 b = *(const bf16x8*)(w0p + ((32 + kc) << 5));
                if (kc & 1) g0B = MFMA(a, b, g0B);
                else        g0A = MFMA(a, b, g0A);
            }
        } else {
            // t == TT: only gates1(TT-1) h0-part
            #pragma unroll 4
            for (int kc = 0; kc < 32; ++kc) {
                const bf16x8 a  = *(const bf16x8*)(h0p + (kc << 5));
                const bf16x8 b1 = *(const bf16x8*)(w1p + (kc << 5));
                if (kc & 1) g1B = MFMA(a, b1, g1B);
                else        g1A = MFMA(a, b1, g1A);
            }
        }
        if (t >= 1) {
            // gates1(t-1) h1-part
            #pragma unroll 4
            for (int kc = 0; kc < 32; ++kc) {
                const bf16x8 a = *(const bf16x8*)(h1p + (kc << 5));
                const bf16x8 b = *(const bf16x8*)(w1p + ((32 + kc) << 5));
                if (kc & 1) g1B = MFMA(a, b, g1B);
                else        g1A = MFMA(a, b, g1A);
            }
        }

        // classifier tiles (lagged; read only already-visible h)
        if (blk < 32 && wave == (blk >> 3) && t >= 1) {           // l0(t-1)
            f32x4 ca = { biasc, biasc, biasc, biasc }, cb = { 0.f, 0.f, 0.f, 0.f };
            const u16* hp = h0rd + arow*HH + kgrp;
            #pragma unroll 4
            for (int kc = 0; kc < 32; ++kc) {
                const bf16x8 a = *(const bf16x8*)(hp + (kc << 5));
                const bf16x8 b = *(const bf16x8*)(wcp + (kc << 5));
                if (kc & 1) cb = MFMA(a, b, cb); else ca = MFMA(a, b, ca);
            }
            const int cc = ((blk & 7) << 4) + col16;
            #pragma unroll
            for (int qq = 0; qq < 4; ++qq) {
                const int br = (wave << 4) + ((lane >> 4) << 2) + qq;
                __builtin_nontemporal_store(ca[qq] + cb[qq],
                    &out[(br*CC + cc)*(2*TT) + ((t - 1) << 1)]);
            }
        }
        if (blk >= 32 && blk < 64 && wave == ((blk - 32) >> 3) && t >= 2) {  // l1(t-2)
            f32x4 ca = { biasc, biasc, biasc, biasc }, cb = { 0.f, 0.f, 0.f, 0.f };
            const u16* hp = h1rd + arow*HH + kgrp;
            #pragma unroll 4
            for (int kc = 0; kc < 32; ++kc) {
                const bf16x8 a = *(const bf16x8*)(hp + (kc << 5));
                const bf16x8 b = *(const bf16x8*)(wcp + (kc << 5));
                if (kc & 1) cb = MFMA(a, b, cb); else ca = MFMA(a, b, ca);
            }
            const int cc = ((blk & 7) << 4) + col16;
            #pragma unroll
            for (int qq = 0; qq < 4; ++qq) {
                const int br = (wave << 4) + ((lane >> 4) << 2) + qq;
                __builtin_nontemporal_store(ca[qq] + cb[qq],
                    &out[(br*CC + cc)*(2*TT) + (((t - 2) << 1) + 1)]);
            }
        }

        // ---- gate scratch -> LDS (same-wave consumption; DS is in-order per wave)
        if (t < TT) {
            #pragma unroll
            for (int qq = 0; qq < 4; ++qq)
                gsc0[wave*272 + (((lane >> 4) << 2) + qq)*17 + col16] = g0A[qq] + g0B[qq];
        }
        if (t >= 1) {
            #pragma unroll
            for (int qq = 0; qq < 4; ++qq)
                gsc1[wave*272 + (((lane >> 4) << 2) + qq)*17 + col16] = g1A[qq] + g1B[qq];
        }
        asm volatile("s_waitcnt lgkmcnt(0)" ::: "memory");

        // ---- elementwise cells; h stores = 8B agent-scope atomics (bypass L2 -> LLC)
        const int rloc = lane >> 2, jj = lane & 3;
        if (t < TT) {
            const float* g = gsc0 + wave*272 + rloc*17;
            const float ig = sigm(g[jj]), fg = sigm(g[4 + jj]);
            const float gt = tanhf(g[8 + jj]), og = sigm(g[12 + jj]);
            c0 = fg*c0 + ig*gt;
            unsigned v = f2bf(og * tanhf(c0));
            unsigned p = v | (__shfl_down(v, 1) << 16);
            ull_t all = ((ull_t)__shfl_down(p, 2) << 32) | (ull_t)p;
            if (jj == 0)
                __hip_atomic_store((ull_t*)(h0wr + ((wave << 4) + rloc)*HH + (blk << 2)),
                                   all, __ATOMIC_RELAXED, __HIP_MEMORY_SCOPE_AGENT);
        }
        if (t >= 1) {
            const float* g = gsc1 + wave*272 + rloc*17;
            const float ig = sigm(g[jj]), fg = sigm(g[4 + jj]);
            const float gt = tanhf(g[8 + jj]), og = sigm(g[12 + jj]);
            c1 = fg*c1 + ig*gt;
            unsigned v = f2bf(og * tanhf(c1));
            unsigned p = v | (__shfl_down(v, 1) << 16);
            ull_t all = ((ull_t)__shfl_down(p, 2) << 32) | (ull_t)p;
            if (jj == 0)
                __hip_atomic_store((ull_t*)(h1wr + ((wave << 4) + rloc)*HH + (blk << 2)),
                                   all, __ATOMIC_RELAXED, __HIP_MEMORY_SCOPE_AGENT);
        }

        // ---- grid barrier: tree arrive (16x16 monotonic) + gen poll, no L2 writeback
        asm volatile("s_waitcnt vmcnt(0)" ::: "memory");   // h stores at coherence point
        __syncthreads();
        if (tid == 0) {
            const unsigned tgt = (unsigned)(16 * (t + 1));
            unsigned ga = __hip_atomic_fetch_add(&bar[(blk >> 4) * 32], 1u,
                              __ATOMIC_RELAXED, __HIP_MEMORY_SCOPE_AGENT) + 1;
            if (ga == tgt) {
                unsigned ta = __hip_atomic_fetch_add(&bar[512], 1u,
                                  __ATOMIC_RELAXED, __HIP_MEMORY_SCOPE_AGENT) + 1;
                if (ta == tgt)
                    __hip_atomic_store(&bar[544], (unsigned)(t + 1),
                                       __ATOMIC_RELAXED, __HIP_MEMORY_SCOPE_AGENT);
            }
            while (__hip_atomic_load(&bar[544], __ATOMIC_RELAXED,
                                     __HIP_MEMORY_SCOPE_AGENT) < (unsigned)(t + 1))
                __builtin_amdgcn_s_sleep(2);
        }
        __syncthreads();
        // drop stale L1/L2 copies of h lines (stores bypassed L2)
        __builtin_amdgcn_fence(__ATOMIC_ACQUIRE, "agent");
    }

    // ---- post-loop: l1(TT-1)
    if (blk >= 32 && blk < 64 && wave == ((blk - 32) >> 3)) {
        f32x4 ca = { biasc, biasc, biasc, biasc }, cb = { 0.f, 0.f, 0.f, 0.f };
        const u16* hp = h1buf[1] + arow*HH + kgrp;   // h1(TT-1)
        #pragma unroll 4
        for (int kc = 0; kc < 32; ++kc) {
            const bf16x8 a = *(const bf16x8*)(hp + (kc << 5));
            const bf16x8 b = *(const bf16x8*)(wcp + (kc << 5));
            if (kc & 1) cb = MFMA(a, b, cb); else ca = MFMA(a, b, ca);
        }
        const int cc = ((blk & 7) << 4) + col16;
        #pragma unroll
        for (int qq = 0; qq < 4; ++qq) {
            const int br = (wave << 4) + ((lane >> 4) << 2) + qq;
            __builtin_nontemporal_store(ca[qq] + cb[qq],
                &out[(br*CC + cc)*(2*TT) + (((TT - 1) << 1) + 1)]);
        }
    }
}

extern "C" void kernel_launch(void* const* d_in, const int* in_sizes, int n_in,
                              void* d_out, int out_size, void* d_ws, size_t ws_size,
                              hipStream_t stream) {
    const float* xs   = (const float*)d_in[0];
    const float* Wih0 = (const float*)d_in[1];
    const float* Whh0 = (const float*)d_in[2];
    const float* bih0 = (const float*)d_in[3];
    const float* bhh0 = (const float*)d_in[4];
    const float* Wih1 = (const float*)d_in[5];
    const float* Whh1 = (const float*)d_in[6];
    const float* bih1 = (const float*)d_in[7];
    const float* bhh1 = (const float*)d_in[8];
    const float* Wcls = (const float*)d_in[9];
    const float* bcls = (const float*)d_in[10];
    float* out = (float*)d_out;
    u16*      hws = (u16*)d_ws;
    unsigned* bar = (unsigned*)((char*)d_ws + WS_HBYTES);

    // zero h buffers + barrier counters (captured; deterministic per replay)
    (void)hipMemsetAsync(d_ws, 0, WS_ZERO_BYTES, stream);

    (void)hipFuncSetAttribute((const void*)lstm_persist,
                              hipFuncAttributeMaxDynamicSharedMemorySize, SMEM_BYTES);

    lstm_persist<<<dim3(256), dim3(256), SMEM_BYTES, stream>>>(
        xs, Wih0, Whh0, bih0, bhh0, Wih1, Whh1, bih1, bhh1, Wcls, bcls,
        out, hws, bar);
}

// Round 4
// 6334.113 us; speedup vs baseline: 3.0475x; 1.1399x over previous
//
#include <hip/hip_runtime.h>

#define BB  64
#define TT  256
#define INF 512
#define HH  1024
#define CC  128

typedef __attribute__((ext_vector_type(8))) short bf16x8;
typedef __attribute__((ext_vector_type(4))) float f32x4;
typedef unsigned long long ull_t;
typedef unsigned short u16;

#define W0_LD 1544   // 1536+8
#define W1_LD 2056   // 2048+8
#define WC_LD 1032   // 1024+8
#define GSC_OFF (16*W0_LD + 16*W1_LD + 16*WC_LD)
#define SMEM_BYTES (GSC_OFF*2 + 2*(4*16*17)*4)   // 156928 B

#define HBUF (BB*HH)                  // elements per h generation
#define WS_HBYTES (8*HBUF*2)          // h0[4] + h1[4] rings, bf16
#define WS_ZERO_BYTES (WS_HBYTES + 2048)

__device__ __forceinline__ u16 f2bf(float f) {
    union { float f; unsigned u; } v; v.f = f;
    unsigned r = v.u + 0x7fffu + ((v.u >> 16) & 1u);   // RNE
    return (u16)(r >> 16);
}
__device__ __forceinline__ float sigm(float x) { return 1.f / (1.f + __expf(-x)); }

#define MFMA(a,b,c) __builtin_amdgcn_mfma_f32_16x16x32_bf16((a),(b),(c),0,0,0)

__global__ __launch_bounds__(256, 1)
void lstm_persist(const float* __restrict__ xs,
                  const float* __restrict__ Wih0, const float* __restrict__ Whh0,
                  const float* __restrict__ bih0, const float* __restrict__ bhh0,
                  const float* __restrict__ Wih1, const float* __restrict__ Whh1,
                  const float* __restrict__ bih1, const float* __restrict__ bhh1,
                  const float* __restrict__ Wcls, const float* __restrict__ bcls,
                  float* __restrict__ out,          // f32 [B][C][2T]
                  u16* __restrict__ hws,            // h rings (bf16)
                  unsigned* __restrict__ bar)       // slots[256] + flag (zeroed)
{
    extern __shared__ char smem[];
    u16* W0s = (u16*)smem;              // [16][W0_LD]  [W_hh0 | W_ih0]
    u16* W1s = W0s + 16*W0_LD;          // [16][W1_LD]  [W_ih1 | W_hh1]
    u16* WCs = W1s + 16*W1_LD;          // [16][WC_LD]  W_cls slice (blocks 0..63)
    float* gsc0 = (float*)(smem + GSC_OFF*2);       // [4][16][17]
    float* gsc1 = gsc0 + 4*16*17;

    const int blk   = blockIdx.x;       // owns h-cols 4*blk..4*blk+3 (both layers)
    const int tid   = threadIdx.x;
    const int wave  = tid >> 6;
    const int lane  = tid & 63;
    const int col16 = lane & 15;
    const int kgrp  = (lane >> 4) << 3;

    // ---- prologue: weights -> LDS (bf16)
    for (int i = tid; i < 16*1536; i += 256) {
        int r = i / 1536, k = i - r*1536;
        int gr = 4*blk + (r & 3) + HH*(r >> 2);
        float v = (k < HH) ? Whh0[gr*HH + k] : Wih0[gr*INF + (k - HH)];
        W0s[r*W0_LD + k] = f2bf(v);
    }
    for (int i = tid; i < 16*2048; i += 256) {
        int r = i >> 11, k = i & 2047;
        int gr = 4*blk + (r & 3) + HH*(r >> 2);
        float v = (k < HH) ? Wih1[gr*HH + k] : Whh1[gr*HH + (k - HH)];
        W1s[r*W1_LD + k] = f2bf(v);
    }
    if (blk < 64) {
        int cb = (blk & 7) << 4;
        for (int i = tid; i < 16*1024; i += 256) {
            int r = i >> 10, k = i & 1023;
            WCs[r*WC_LD + k] = f2bf(Wcls[(cb + r)*HH + k]);
        }
    }
    const int   grl   = 4*blk + (col16 & 3) + HH*(col16 >> 2);
    const float bias0 = bih0[grl] + bhh0[grl];
    const float bias1 = bih1[grl] + bhh1[grl];
    const float biasc = (blk < 64) ? bcls[((blk & 7) << 4) + col16] : 0.f;

    float c0 = 0.f, c1 = 0.f;
    __syncthreads();

    const int  arow = (wave << 4) + col16;
    const u16* w0p  = W0s + col16*W0_LD + kgrp;
    const u16* w1p  = W1s + col16*W1_LD + kgrp;
    const u16* wcp  = WCs + col16*WC_LD + kgrp;

#define XPART(tx) do { \
        const float* xp = xs + (arow*TT + (tx))*INF + kgrp; \
        _Pragma("unroll 4") \
        for (int kc = 0; kc < 16; ++kc) { \
            const float4 x0 = *(const float4*)(xp + (kc << 5)); \
            const float4 x1 = *(const float4*)(xp + (kc << 5) + 4); \
            bf16x8 a; \
            a[0]=(short)f2bf(x0.x); a[1]=(short)f2bf(x0.y); a[2]=(short)f2bf(x0.z); a[3]=(short)f2bf(x0.w); \
            a[4]=(short)f2bf(x1.x); a[5]=(short)f2bf(x1.y); a[6]=(short)f2bf(x1.z); a[7]=(short)f2bf(x1.w); \
            const bf16x8 b = *(const bf16x8*)(w0p + ((32 + kc) << 5)); \
            if (kc & 1) g0B = MFMA(a, b, g0B); else g0A = MFMA(a, b, g0A); \
        } } while (0)

#define CLS(hbase, tcol) do { \
        f32x4 ca = { biasc, biasc, biasc, biasc }, cd = { 0.f, 0.f, 0.f, 0.f }; \
        const u16* hp = (hbase) + arow*HH + kgrp; \
        _Pragma("unroll 4") \
        for (int kc = 0; kc < 32; ++kc) { \
            const bf16x8 a = *(const bf16x8*)(hp + (kc << 5)); \
            const bf16x8 b = *(const bf16x8*)(wcp + (kc << 5)); \
            if (kc & 1) cd = MFMA(a, b, cd); else ca = MFMA(a, b, ca); \
        } \
        const int cc = ((blk & 7) << 4) + col16; \
        _Pragma("unroll") \
        for (int qq = 0; qq < 4; ++qq) { \
            const int br = (wave << 4) + ((lane >> 4) << 2) + qq; \
            __builtin_nontemporal_store(ca[qq] + cd[qq], &out[(br*CC + cc)*(2*TT) + (tcol)]); \
        } } while (0)

    f32x4 g0A = { bias0, bias0, bias0, bias0 }, g0B = { 0.f, 0.f, 0.f, 0.f };
    XPART(0);   // prime x-projection for t=0

    for (int t = 0; t <= TT; ++t) {
        const u16* h0rd = hws + (unsigned)((t + 3) & 3)*HBUF;            // h0(t-1)
        u16*       h0wr = hws + (unsigned)(t & 3)*HBUF;                  // h0(t)
        const u16* h1rd = hws + 4*HBUF + (unsigned)((t + 2) & 3)*HBUF;   // h1(t-2)
        u16*       h1wr = hws + 4*HBUF + (unsigned)((t + 3) & 3)*HBUF;   // h1(t-1)

        f32x4 g1A = { bias1, bias1, bias1, bias1 }, g1B = { 0.f, 0.f, 0.f, 0.f };

        // ---- post-wait critical path: depends on h0(t-1), h1(t-2)
        if (t >= 1 && t < TT) {
            const u16* h0p = h0rd + arow*HH + kgrp;
            #pragma unroll 4
            for (int kc = 0; kc < 32; ++kc) {   // fused: shared A-frag
                const bf16x8 a  = *(const bf16x8*)(h0p + (kc << 5));
                const bf16x8 b0 = *(const bf16x8*)(w0p + (kc << 5));
                const bf16x8 b1 = *(const bf16x8*)(w1p + (kc << 5));
                if (kc & 1) { g0B = MFMA(a, b0, g0B); g1B = MFMA(a, b1, g1B); }
                else        { g0A = MFMA(a, b0, g0A); g1A = MFMA(a, b1, g1A); }
            }
        } else if (t == TT) {
            const u16* h0p = h0rd + arow*HH + kgrp;
            #pragma unroll 4
            for (int kc = 0; kc < 32; ++kc) {
                const bf16x8 a  = *(const bf16x8*)(h0p + (kc << 5));
                const bf16x8 b1 = *(const bf16x8*)(w1p + (kc << 5));
                if (kc & 1) g1B = MFMA(a, b1, g1B);
                else        g1A = MFMA(a, b1, g1A);
            }
        }
        if (t >= 1) {
            const u16* h1p = h1rd + arow*HH + kgrp;
            #pragma unroll 4
            for (int kc = 0; kc < 32; ++kc) {
                const bf16x8 a = *(const bf16x8*)(h1p + (kc << 5));
                const bf16x8 b = *(const bf16x8*)(w1p + ((32 + kc) << 5));
                if (kc & 1) g1B = MFMA(a, b, g1B);
                else        g1A = MFMA(a, b, g1A);
            }
        }

        if (t < TT) {
            #pragma unroll
            for (int qq = 0; qq < 4; ++qq)
                gsc0[wave*272 + (((lane >> 4) << 2) + qq)*17 + col16] = g0A[qq] + g0B[qq];
        }
        if (t >= 1) {
            #pragma unroll
            for (int qq = 0; qq < 4; ++qq)
                gsc1[wave*272 + (((lane >> 4) << 2) + qq)*17 + col16] = g1A[qq] + g1B[qq];
        }
        asm volatile("s_waitcnt lgkmcnt(0)" ::: "memory");

        const int rloc = lane >> 2, jj = lane & 3;
        if (t < TT) {
            const float* g = gsc0 + wave*272 + rloc*17;
            const float ig = sigm(g[jj]), fg = sigm(g[4 + jj]);
            const float gt = tanhf(g[8 + jj]), og = sigm(g[12 + jj]);
            c0 = fg*c0 + ig*gt;
            unsigned v = f2bf(og * tanhf(c0));
            unsigned p = v | (__shfl_down(v, 1) << 16);
            ull_t all = ((ull_t)__shfl_down(p, 2) << 32) | (ull_t)p;
            if (jj == 0)
                __hip_atomic_store((ull_t*)(h0wr + ((wave << 4) + rloc)*HH + (blk << 2)),
                                   all, __ATOMIC_RELAXED, __HIP_MEMORY_SCOPE_AGENT);
        }
        if (t >= 1) {
            const float* g = gsc1 + wave*272 + rloc*17;
            const float ig = sigm(g[jj]), fg = sigm(g[4 + jj]);
            const float gt = tanhf(g[8 + jj]), og = sigm(g[12 + jj]);
            c1 = fg*c1 + ig*gt;
            unsigned v = f2bf(og * tanhf(c1));
            unsigned p = v | (__shfl_down(v, 1) << 16);
            ull_t all = ((ull_t)__shfl_down(p, 2) << 32) | (ull_t)p;
            if (jj == 0)
                __hip_atomic_store((ull_t*)(h1wr + ((wave << 4) + rloc)*HH + (blk << 2)),
                                   all, __ATOMIC_RELAXED, __HIP_MEMORY_SCOPE_AGENT);
        }

        // ---- arrive (h stores drained to coherence point first)
        asm volatile("s_waitcnt vmcnt(0)" ::: "memory");
        __syncthreads();
        if (tid == 0)
            __hip_atomic_store(&bar[blk], (unsigned)(t + 1),
                               __ATOMIC_RELAXED, __HIP_MEMORY_SCOPE_AGENT);

        // ---- hidden pre-wait work (independent of barrier t)
        if (t + 1 < TT) {                 // x-projection for next step
            g0A[0] = bias0; g0A[1] = bias0; g0A[2] = bias0; g0A[3] = bias0;
            g0B[0] = 0.f;   g0B[1] = 0.f;   g0B[2] = 0.f;   g0B[3] = 0.f;
            XPART(t + 1);
        }
        if (blk < 32 && wave == (blk >> 3) && t >= 1)                    // l0(t-1)
            CLS(h0rd, ((t - 1) << 1));
        if (blk >= 32 && blk < 64 && wave == ((blk - 32) >> 3) && t >= 2) // l1(t-2)
            CLS(h1rd, (((t - 2) << 1) + 1));

        // ---- wait: aggregator (block 255) scans slots; others poll flag
        if (blk == 255) {
            if (tid < 64) {
                const unsigned tg = (unsigned)(t + 1);
                const ull_t pat = ((ull_t)tg << 32) | (ull_t)tg;
                const ull_t* sp = (const ull_t*)bar + (tid << 1);
                for (;;) {
                    ull_t a = __hip_atomic_load(sp,     __ATOMIC_RELAXED, __HIP_MEMORY_SCOPE_AGENT);
                    ull_t b = __hip_atomic_load(sp + 1, __ATOMIC_RELAXED, __HIP_MEMORY_SCOPE_AGENT);
                    if (__all((a == pat) && (b == pat))) break;
                }
                if (tid == 0)
                    __hip_atomic_store(&bar[320], (unsigned)(t + 1),
                                       __ATOMIC_RELAXED, __HIP_MEMORY_SCOPE_AGENT);
            }
        } else if (tid == 0) {
            while (__hip_atomic_load(&bar[320], __ATOMIC_RELAXED,
                                     __HIP_MEMORY_SCOPE_AGENT) < (unsigned)(t + 1))
                __builtin_amdgcn_s_sleep(1);
        }
        __syncthreads();
        __builtin_amdgcn_fence(__ATOMIC_ACQUIRE, "agent");
    }

    // ---- post-loop: l1(TT-1)
    if (blk >= 32 && blk < 64 && wave == ((blk - 32) >> 3))
        CLS(hws + 4*HBUF + (unsigned)((TT - 1) & 3)*HBUF, (((TT - 1) << 1) + 1));
}

extern "C" void kernel_launch(void* const* d_in, const int* in_sizes, int n_in,
                              void* d_out, int out_size, void* d_ws, size_t ws_size,
                              hipStream_t stream) {
    const float* xs   = (const float*)d_in[0];
    const float* Wih0 = (const float*)d_in[1];
    const float* Whh0 = (const float*)d_in[2];
    const float* bih0 = (const float*)d_in[3];
    const float* bhh0 = (const float*)d_in[4];
    const float* Wih1 = (const float*)d_in[5];
    const float* Whh1 = (const float*)d_in[6];
    const float* bih1 = (const float*)d_in[7];
    const float* bhh1 = (const float*)d_in[8];
    const float* Wcls = (const float*)d_in[9];
    const float* bcls = (const float*)d_in[10];
    float* out = (float*)d_out;
    u16*      hws = (u16*)d_ws;
    unsigned* bar = (unsigned*)((char*)d_ws + WS_HBYTES);

    (void)hipMemsetAsync(d_ws, 0, WS_ZERO_BYTES, stream);

    (void)hipFuncSetAttribute((const void*)lstm_persist,
                              hipFuncAttributeMaxDynamicSharedMemorySize, SMEM_BYTES);

    lstm_persist<<<dim3(256), dim3(256), SMEM_BYTES, stream>>>(
        xs, Wih0, Whh0, bih0, bhh0, Wih1, Whh1, bih1, bhh1, Wcls, bcls,
        out, hws, bar);
}